// Round 1
// baseline (537.932 us; speedup 1.0000x reference)
//
#include <hip/hip_runtime.h>
#include <hip/hip_bf16.h>

typedef unsigned short u16;
typedef short bf16x8 __attribute__((ext_vector_type(8)));
typedef float f32x4 __attribute__((ext_vector_type(4)));
typedef unsigned short ushortx8 __attribute__((ext_vector_type(8)));

#define GPTR(p)  ((const __attribute__((address_space(1))) void*)(p))
#define LDSPTR(p) ((__attribute__((address_space(3))) void*)(p))

static __device__ __forceinline__ float bf2f(u16 u) {
    union { unsigned int i; float f; } v; v.i = ((unsigned int)u) << 16; return v.f;
}
static __device__ __forceinline__ u16 f2bf(float f) {
    union { float f; unsigned int i; } v; v.f = f;
    unsigned int u = v.i;
    return (u16)((u + 0x7fffu + ((u >> 16) & 1u)) >> 16);
}

// ---------------- weight convert: fp32 -> bf16 ----------------
__global__ __launch_bounds__(256) void cvtw_kernel(
    const float* __restrict__ wu, const float* __restrict__ wf,
    u16* __restrict__ wub, u16* __restrict__ wfb) {
    int i = blockIdx.x * 256 + threadIdx.x;   // 262144 total
    wub[i] = f2bf(wu[i]);
    wfb[i] = f2bf(wf[i]);
}

// ---------------- 8x8 avg pool: x[n][c][56][56] -> pooled[n][c][7][7] ----------------
__global__ __launch_bounds__(256) void pool_kernel(
    const float* __restrict__ x, float* __restrict__ pooled) {
    __shared__ float plane[3136];
    size_t nc = blockIdx.x;                   // n*512 + c
    const float4* xp = (const float4*)(x + nc * 3136);
    float4* pl = (float4*)plane;
    for (int i = threadIdx.x; i < 784; i += 256) pl[i] = xp[i];
    __syncthreads();
    int t = threadIdx.x;
    if (t < 49) {
        int py = t / 7, px = t - py * 7;
        float s = 0.f;
        #pragma unroll
        for (int r = 0; r < 8; ++r)
            #pragma unroll
            for (int col = 0; col < 8; ++col)
                s += plane[(py * 8 + r) * 56 + px * 8 + col];
        pooled[nc * 49 + t] = s * (1.0f / 64.0f);
    }
}

// ---------------- transpose+convert: x[n][c][3136] fp32 -> x_t[n*3136+j][c] bf16 ----------------
__global__ __launch_bounds__(256) void transpose_kernel(
    const float* __restrict__ x, u16* __restrict__ xt) {
    __shared__ float tile[64][65];
    int bid = blockIdx.x;
    int jt = bid % 49;
    int r = bid / 49;
    int ct = r & 7, n = r >> 3;
    const float* src = x + ((size_t)(n * 512 + ct * 64)) * 3136 + jt * 64;
    for (int e = threadIdx.x; e < 4096; e += 256) {
        int i = e >> 6, jj = e & 63;
        tile[i][jj] = src[(size_t)i * 3136 + jj];
    }
    __syncthreads();
    u16* dst = xt + ((size_t)(n * 3136 + jt * 64)) * 512 + ct * 64;
    for (int e = threadIdx.x; e < 2048; e += 256) {
        int jj = e >> 5, i2 = (e & 31) * 2;
        unsigned int val = (unsigned)f2bf(tile[i2][jj]) | ((unsigned)f2bf(tile[i2 + 1][jj]) << 16);
        *(unsigned int*)(dst + (size_t)jj * 512 + i2) = val;
    }
}

// ---------------- down conv1x1: pooled[n][512][49] x w_down[512][512] -> down[n][512][49] fp32 ----------------
__global__ __launch_bounds__(256) void down_kernel(
    const float* __restrict__ pooled, const float* __restrict__ w_down,
    const float* __restrict__ b_down, float* __restrict__ down) {
    int bid = blockIdx.x;
    int n = bid >> 5, og = bid & 31;
    int wv = threadIdx.x >> 6, lane = threadIdx.x & 63;
    int o0 = og * 16 + wv * 4;
    const float* pp = pooled + (size_t)n * 512 * 49;
    const float* w0 = w_down + (size_t)o0 * 512;
    float a0 = 0, a1 = 0, a2 = 0, a3 = 0;
    int cell = lane < 49 ? lane : 48;
    #pragma unroll 4
    for (int c = 0; c < 512; ++c) {
        float p = pp[c * 49 + cell];
        a0 += p * w0[c];
        a1 += p * w0[512 + c];
        a2 += p * w0[1024 + c];
        a3 += p * w0[1536 + c];
    }
    if (lane < 49) {
        float* dd = down + ((size_t)n * 512 + o0) * 49 + lane;
        dd[0]   = a0 + b_down[o0];
        dd[49]  = a1 + b_down[o0 + 1];
        dd[98]  = a2 + b_down[o0 + 2];
        dd[147] = a3 + b_down[o0 + 3];
    }
}

// ---------------- GEMM (m97 structure): C[m][n] = sum_k A[m][k] * Bt[n][k] ----------------
// EPI=0: up GEMM.  A=x_t [100352][512], Bt=w_up_bf16 [512][512], bias by col, bf16 out [100352][512]
// EPI=1: final GEMM. A=w_final_bf16 [512][512], Bt=dw [100352][512], bias by row, fp32 out NCHW
template <int EPI>
__global__ __launch_bounds__(256) void gemm_kernel(
    const u16* __restrict__ A, const u16* __restrict__ Bt,
    const float* __restrict__ bias, void* __restrict__ Cout) {
    constexpr int K = 512;
    __shared__ u16 As[128 * 32];
    __shared__ u16 Bs[128 * 32];
    int tid = threadIdx.x, wv = tid >> 6, lane = tid & 63;
    int bid = blockIdx.x;
    int tm, tn;
    if (EPI == 0) { tm = bid >> 2; tn = bid & 3; }     // 4 consecutive blocks share A-tile
    else          { tm = bid & 3;  tn = bid >> 2; }    // 4 consecutive blocks share B-tile
    size_t m0 = (size_t)tm * 128, n0 = (size_t)tn * 128;
    int lr = lane & 15, lk = (lane >> 4) * 8;
    int wr = wv >> 1, wc = wv & 1;

    int e0 = wv * 512 + lane * 8;
    int e1 = e0 + 2048;
    const u16* pa0 = A + (m0 + (size_t)(e0 >> 5)) * K + (e0 & 31);
    const u16* pa1 = A + (m0 + (size_t)(e1 >> 5)) * K + (e1 & 31);
    const u16* pb0 = Bt + (n0 + (size_t)(e0 >> 5)) * K + (e0 & 31);
    const u16* pb1 = Bt + (n0 + (size_t)(e1 >> 5)) * K + (e1 & 31);
    u16* sa0 = &As[wv * 512]; u16* sa1 = &As[wv * 512 + 2048];
    u16* sb0 = &Bs[wv * 512]; u16* sb1 = &Bs[wv * 512 + 2048];

    f32x4 acc[4][4] = {};

    for (int kt = 0; kt < K / 32; ++kt) {
        __builtin_amdgcn_global_load_lds(GPTR(pa0), LDSPTR(sa0), 16, 0, 0);
        __builtin_amdgcn_global_load_lds(GPTR(pa1), LDSPTR(sa1), 16, 0, 0);
        __builtin_amdgcn_global_load_lds(GPTR(pb0), LDSPTR(sb0), 16, 0, 0);
        __builtin_amdgcn_global_load_lds(GPTR(pb1), LDSPTR(sb1), 16, 0, 0);
        pa0 += 32; pa1 += 32; pb0 += 32; pb1 += 32;
        __syncthreads();
        bf16x8 af[4], bfr[4];
        #pragma unroll
        for (int mi = 0; mi < 4; ++mi)
            af[mi] = *(const bf16x8*)&As[(wr * 64 + mi * 16 + lr) * 32 + lk];
        #pragma unroll
        for (int ni = 0; ni < 4; ++ni)
            bfr[ni] = *(const bf16x8*)&Bs[(wc * 64 + ni * 16 + lr) * 32 + lk];
        #pragma unroll
        for (int mi = 0; mi < 4; ++mi)
            #pragma unroll
            for (int ni = 0; ni < 4; ++ni)
                acc[mi][ni] = __builtin_amdgcn_mfma_f32_16x16x32_bf16(af[mi], bfr[ni], acc[mi][ni], 0, 0, 0);
        __syncthreads();
    }

    if (EPI == 0) {
        u16* C = (u16*)Cout;
        #pragma unroll
        for (int ni = 0; ni < 4; ++ni) {
            size_t col = n0 + wc * 64 + ni * 16 + lr;
            float bv = bias[col];
            #pragma unroll
            for (int mi = 0; mi < 4; ++mi) {
                size_t row = m0 + wr * 64 + mi * 16 + (lane >> 4) * 4;
                #pragma unroll
                for (int r = 0; r < 4; ++r)
                    C[(row + r) * 512 + col] = f2bf(acc[mi][ni][r] + bv);
            }
        }
    } else {
        float* C = (float*)Cout;
        #pragma unroll
        for (int ni = 0; ni < 4; ++ni) {
            int col = (int)(n0 + wc * 64 + ni * 16 + lr);   // flat J
            int nimg = col / 3136;
            int jj = col - nimg * 3136;
            size_t obase = (size_t)nimg * 512 * 3136 + jj;
            #pragma unroll
            for (int mi = 0; mi < 4; ++mi) {
                int row = (int)(m0 + wr * 64 + mi * 16 + (lane >> 4) * 4);
                #pragma unroll
                for (int r = 0; r < 4; ++r)
                    C[obase + (size_t)(row + r) * 3136] = acc[mi][ni][r] + bias[row + r];
            }
        }
    }
}

// ---------------- dynamic depthwise 7x7 (NHWC) ----------------
// up[J][512] bf16, down[n][512][49] fp32 -> dw[J][512] bf16
__global__ __launch_bounds__(256) void dw_kernel(
    const u16* __restrict__ up, const float* __restrict__ down,
    u16* __restrict__ dw) {
    __shared__ u16 tileL[14 * 64 * 32];   // [hh][wc pad 64][32 ch]
    __shared__ float kbuf[32 * 49];
    int bid = blockIdx.x;
    int n = bid / 112;
    int rem = bid - n * 112;
    int rt = rem >> 4, cg = rem & 15;
    int tid = threadIdx.x;

    const float* dsrc = down + ((size_t)n * 512 + cg * 32) * 49;
    for (int e = tid; e < 1568; e += 256) kbuf[e] = dsrc[e];

    for (int e = tid; e < 3472; e += 256) {   // 14 rows * 62 cols * 4 octets
        int p = e >> 2, q = e & 3;
        int hh = p / 62, wcol = p - hh * 62;
        int h = rt * 8 + hh - 3, w = wcol - 3;
        ushortx8 v = (ushortx8)0;
        if (h >= 0 && h < 56 && w >= 0 && w < 56)
            v = *(const ushortx8*)(up + ((size_t)(n * 3136 + h * 56 + w)) * 512 + cg * 32 + q * 8);
        *(ushortx8*)&tileL[(hh * 64 + wcol) * 32 + q * 8] = v;
    }
    __syncthreads();

    int c = tid & 31, g = tid >> 5;
    const int oh = g;
    #pragma unroll 1
    for (int wseg = 0; wseg < 8; ++wseg) {
        float acc[7] = {0, 0, 0, 0, 0, 0, 0};
        #pragma unroll
        for (int ky = 0; ky < 7; ++ky) {
            float v[13];
            #pragma unroll
            for (int t2 = 0; t2 < 13; ++t2)
                v[t2] = bf2f(tileL[((oh + ky) * 64 + wseg * 7 + t2) * 32 + c]);
            #pragma unroll
            for (int kx = 0; kx < 7; ++kx) {
                float kk = kbuf[c * 49 + ky * 7 + kx];
                #pragma unroll
                for (int i = 0; i < 7; ++i) acc[i] += v[i + kx] * kk;
            }
        }
        int h = rt * 8 + oh;
        #pragma unroll
        for (int i = 0; i < 7; ++i) {
            int w = wseg * 7 + i;
            dw[((size_t)(n * 3136 + h * 56 + w)) * 512 + cg * 32 + c] = f2bf(acc[i]);
        }
    }
}

extern "C" void kernel_launch(void* const* d_in, const int* in_sizes, int n_in,
                              void* d_out, int out_size, void* d_ws, size_t ws_size,
                              hipStream_t stream) {
    const float* x       = (const float*)d_in[0];
    // d_in[1] = k (=7), hardcoded
    const float* w_up    = (const float*)d_in[2];
    const float* b_up    = (const float*)d_in[3];
    const float* w_down  = (const float*)d_in[4];
    const float* b_down  = (const float*)d_in[5];
    const float* w_final = (const float*)d_in[6];
    const float* b_final = (const float*)d_in[7];

    char* ws = (char*)d_ws;
    u16*   xt     = (u16*)  (ws + 0);            // 102,760,448 B (x_t; later aliased as dw)
    u16*   up     = (u16*)  (ws + 102760448);    // 102,760,448 B
    float* pooled = (float*)(ws + 205520896);    // 3,211,264 B
    float* down   = (float*)(ws + 208732160);    // 3,211,264 B
    u16*   wub    = (u16*)  (ws + 211943424);    // 524,288 B
    u16*   wfb    = (u16*)  (ws + 212467712);    // 524,288 B
    u16*   dwb    = xt;                          // alias (x_t dead after up GEMM)

    cvtw_kernel<<<1024, 256, 0, stream>>>(w_up, w_final, wub, wfb);
    pool_kernel<<<16384, 256, 0, stream>>>(x, pooled);
    transpose_kernel<<<12544, 256, 0, stream>>>(x, xt);
    down_kernel<<<1024, 256, 0, stream>>>(pooled, w_down, b_down, down);
    gemm_kernel<0><<<3136, 256, 0, stream>>>(xt, wub, b_up, up);
    dw_kernel<<<3584, 256, 0, stream>>>(up, down, dwb);
    gemm_kernel<1><<<3136, 256, 0, stream>>>(wfb, dwb, b_final, d_out);
}

// Round 2
// 487.710 us; speedup vs baseline: 1.1030x; 1.1030x over previous
//
#include <hip/hip_runtime.h>
#include <hip/hip_bf16.h>

typedef unsigned short u16;
typedef _Float16 f16x8 __attribute__((ext_vector_type(8)));
typedef _Float16 half2v __attribute__((ext_vector_type(2)));
typedef float f32x4 __attribute__((ext_vector_type(4)));
typedef unsigned short ushortx8 __attribute__((ext_vector_type(8)));

#define GPTR(p)  ((const __attribute__((address_space(1))) void*)(p))
#define LDSPTR(p) ((__attribute__((address_space(3))) void*)(p))

static __device__ __forceinline__ u16 f2h(float f) {
    _Float16 h = (_Float16)f;
    union { _Float16 h; u16 u; } v; v.h = h; return v.u;
}

// ---------------- weight convert: fp32 -> f16 ----------------
__global__ __launch_bounds__(256) void cvtw_kernel(
    const float* __restrict__ wu, const float* __restrict__ wf,
    u16* __restrict__ wub, u16* __restrict__ wfb) {
    int i = blockIdx.x * 256 + threadIdx.x;   // 262144 total
    wub[i] = f2h(wu[i]);
    wfb[i] = f2h(wf[i]);
}

// ---------------- transpose+convert: x[n][c][3136] fp32 -> x_t[n*3136+j][c] f16 ----------------
__global__ __launch_bounds__(256) void transpose_kernel(
    const float* __restrict__ x, u16* __restrict__ xt) {
    __shared__ float tile[64][65];
    int bid = blockIdx.x;
    int jt = bid % 49;
    int r = bid / 49;
    int ct = r & 7, n = r >> 3;
    const float* src = x + ((size_t)(n * 512 + ct * 64)) * 3136 + jt * 64;
    for (int e = threadIdx.x; e < 4096; e += 256) {
        int i = e >> 6, jj = e & 63;
        tile[i][jj] = src[(size_t)i * 3136 + jj];
    }
    __syncthreads();
    u16* dst = xt + ((size_t)(n * 3136 + jt * 64)) * 512 + ct * 64;
    for (int e = threadIdx.x; e < 2048; e += 256) {
        int jj = e >> 5, i2 = (e & 31) * 2;
        unsigned int val = (unsigned)f2h(tile[i2][jj]) | ((unsigned)f2h(tile[i2 + 1][jj]) << 16);
        *(unsigned int*)(dst + (size_t)jj * 512 + i2) = val;
    }
}

// ---------------- 8x8 avg pool from x_t f16: -> pooled[n][512][49] fp32 ----------------
__global__ __launch_bounds__(256) void poolh_kernel(
    const u16* __restrict__ xt, float* __restrict__ pooled) {
    int bid = blockIdx.x;                 // n(32) x py(7) x px(7)
    int n = bid / 49, cell = bid - n * 49;
    int py = cell / 7, px = cell - py * 7;
    int t = threadIdx.x;                  // channel pair 2t, 2t+1
    float s0 = 0.f, s1 = 0.f;
    for (int r = 0; r < 8; ++r) {
        int h = py * 8 + r;
        const u16* base = xt + ((size_t)(n * 3136 + h * 56 + px * 8)) * 512 + 2 * t;
        #pragma unroll
        for (int cc = 0; cc < 8; ++cc) {
            half2v v = *(const half2v*)(base + (size_t)cc * 512);
            s0 += (float)v[0]; s1 += (float)v[1];
        }
    }
    float* pp = pooled + (size_t)n * 512 * 49 + py * 7 + px;
    pp[(size_t)(2 * t) * 49]     = s0 * (1.f / 64.f);
    pp[(size_t)(2 * t + 1) * 49] = s1 * (1.f / 64.f);
}

// ---------------- down conv1x1: pooled[n][512][49] x w_down[512][512] -> down[n][512][49] fp32 ----------------
__global__ __launch_bounds__(256) void down_kernel(
    const float* __restrict__ pooled, const float* __restrict__ w_down,
    const float* __restrict__ b_down, float* __restrict__ down) {
    int bid = blockIdx.x;
    int n = bid >> 5, og = bid & 31;
    int wv = threadIdx.x >> 6, lane = threadIdx.x & 63;
    int o0 = og * 16 + wv * 4;
    const float* pp = pooled + (size_t)n * 512 * 49;
    const float* w0 = w_down + (size_t)o0 * 512;
    float a0 = 0, a1 = 0, a2 = 0, a3 = 0;
    int cell = lane < 49 ? lane : 48;
    #pragma unroll 4
    for (int c = 0; c < 512; ++c) {
        float p = pp[c * 49 + cell];
        a0 += p * w0[c];
        a1 += p * w0[512 + c];
        a2 += p * w0[1024 + c];
        a3 += p * w0[1536 + c];
    }
    if (lane < 49) {
        float* dd = down + ((size_t)n * 512 + o0) * 49 + lane;
        dd[0]   = a0 + b_down[o0];
        dd[49]  = a1 + b_down[o0 + 1];
        dd[98]  = a2 + b_down[o0 + 2];
        dd[147] = a3 + b_down[o0 + 3];
    }
}

// ---------------- GEMM (m97 structure, f16): C[m][n] = sum_k A[m][k] * Bt[n][k] ----------------
// EPI=0: up GEMM.  A=x_t [100352][512], Bt=w_up_f16 [512][512], bias by col, f16 out [100352][512]
// EPI=1: final GEMM. A=w_final_f16 [512][512], Bt=dw [100352][512], bias by row, fp32 out NCHW
template <int EPI>
__global__ __launch_bounds__(256) void gemm_kernel(
    const u16* __restrict__ A, const u16* __restrict__ Bt,
    const float* __restrict__ bias, void* __restrict__ Cout) {
    constexpr int K = 512;
    __shared__ u16 As[128 * 32];
    __shared__ u16 Bs[128 * 32];
    int tid = threadIdx.x, wv = tid >> 6, lane = tid & 63;
    int bid = blockIdx.x;
    int tm, tn;
    if (EPI == 0) { tm = bid >> 2; tn = bid & 3; }
    else          { tm = bid & 3;  tn = bid >> 2; }
    size_t m0 = (size_t)tm * 128, n0 = (size_t)tn * 128;
    int lr = lane & 15, lk = (lane >> 4) * 8;
    int wr = wv >> 1, wc = wv & 1;

    int e0 = wv * 512 + lane * 8;
    int e1 = e0 + 2048;
    const u16* pa0 = A + (m0 + (size_t)(e0 >> 5)) * K + (e0 & 31);
    const u16* pa1 = A + (m0 + (size_t)(e1 >> 5)) * K + (e1 & 31);
    const u16* pb0 = Bt + (n0 + (size_t)(e0 >> 5)) * K + (e0 & 31);
    const u16* pb1 = Bt + (n0 + (size_t)(e1 >> 5)) * K + (e1 & 31);
    u16* sa0 = &As[wv * 512]; u16* sa1 = &As[wv * 512 + 2048];
    u16* sb0 = &Bs[wv * 512]; u16* sb1 = &Bs[wv * 512 + 2048];

    f32x4 acc[4][4] = {};

    for (int kt = 0; kt < K / 32; ++kt) {
        __builtin_amdgcn_global_load_lds(GPTR(pa0), LDSPTR(sa0), 16, 0, 0);
        __builtin_amdgcn_global_load_lds(GPTR(pa1), LDSPTR(sa1), 16, 0, 0);
        __builtin_amdgcn_global_load_lds(GPTR(pb0), LDSPTR(sb0), 16, 0, 0);
        __builtin_amdgcn_global_load_lds(GPTR(pb1), LDSPTR(sb1), 16, 0, 0);
        pa0 += 32; pa1 += 32; pb0 += 32; pb1 += 32;
        __syncthreads();
        f16x8 af[4], bfr[4];
        #pragma unroll
        for (int mi = 0; mi < 4; ++mi)
            af[mi] = *(const f16x8*)&As[(wr * 64 + mi * 16 + lr) * 32 + lk];
        #pragma unroll
        for (int ni = 0; ni < 4; ++ni)
            bfr[ni] = *(const f16x8*)&Bs[(wc * 64 + ni * 16 + lr) * 32 + lk];
        #pragma unroll
        for (int mi = 0; mi < 4; ++mi)
            #pragma unroll
            for (int ni = 0; ni < 4; ++ni)
                acc[mi][ni] = __builtin_amdgcn_mfma_f32_16x16x32_f16(af[mi], bfr[ni], acc[mi][ni], 0, 0, 0);
        __syncthreads();
    }

    if (EPI == 0) {
        u16* C = (u16*)Cout;
        #pragma unroll
        for (int ni = 0; ni < 4; ++ni) {
            size_t col = n0 + wc * 64 + ni * 16 + lr;
            float bv = bias[col];
            #pragma unroll
            for (int mi = 0; mi < 4; ++mi) {
                size_t row = m0 + wr * 64 + mi * 16 + (lane >> 4) * 4;
                #pragma unroll
                for (int r = 0; r < 4; ++r)
                    C[(row + r) * 512 + col] = f2h(acc[mi][ni][r] + bv);
            }
        }
    } else {
        float* C = (float*)Cout;
        #pragma unroll
        for (int ni = 0; ni < 4; ++ni) {
            int col = (int)(n0 + wc * 64 + ni * 16 + lr);   // flat J
            int nimg = col / 3136;
            int jj = col - nimg * 3136;
            size_t obase = (size_t)nimg * 512 * 3136 + jj;
            #pragma unroll
            for (int mi = 0; mi < 4; ++mi) {
                int row = (int)(m0 + wr * 64 + mi * 16 + (lane >> 4) * 4);
                #pragma unroll
                for (int r = 0; r < 4; ++r)
                    C[obase + (size_t)(row + r) * 3136] = acc[mi][ni][r] + bias[row + r];
            }
        }
    }
}

// ---------------- dynamic depthwise 7x7 (f16, v_dot2_f32_f16) ----------------
// up[J][512] f16, down[n][512][49] fp32 -> dw[J][512] f16
// Block: 16 channels x 8 output rows x 56 cols. Grid: 32n x 7rt x 32cg = 7168.
// LDS: per-channel planes [16][14*64] f16, plane stride 449 dwords (898 u16) -> conflict-free.
__global__ __launch_bounds__(256) void dw_kernel(
    const u16* __restrict__ up, const float* __restrict__ down,
    u16* __restrict__ dw) {
    __shared__ u16 tile[16 * 898];        // 28736 B
    int bid = blockIdx.x;
    int n = bid / 224;                    // 7 * 32
    int rem = bid - n * 224;
    int rt = rem >> 5;                    // 0..6
    int cg = rem & 31;                    // 16-ch group
    int tid = threadIdx.x;

    // stage 14 rows x 62 cols x 16 ch (transpose 8-ch vectors into planes)
    for (int e = tid; e < 1736; e += 256) {   // 868 positions x 2 halves
        int p = e >> 1, q = e & 1;
        int hh = p / 62, wcol = p - hh * 62;
        int h = rt * 8 + hh - 3, w = wcol - 3;
        ushortx8 v = (ushortx8)0;
        if (h >= 0 && h < 56 && (unsigned)w < 56u)
            v = *(const ushortx8*)(up + ((size_t)(n * 3136 + h * 56 + w)) * 512 + cg * 16 + q * 8);
        #pragma unroll
        for (int j = 0; j < 8; ++j)
            tile[(q * 8 + j) * 898 + hh * 64 + wcol] = (u16)v[j];
    }

    // kernel taps -> registers, pre-paired for even/odd outputs
    int c = tid & 15, u = tid >> 4;
    int row = u >> 1, sh = u & 1;
    const float* kp = down + ((size_t)n * 512 + cg * 16 + c) * 49;
    half2v ke[7][4], ko[7][4];
    #pragma unroll
    for (int ky = 0; ky < 7; ++ky) {
        float k0 = kp[ky*7+0], k1 = kp[ky*7+1], k2 = kp[ky*7+2], k3 = kp[ky*7+3];
        float k4 = kp[ky*7+4], k5 = kp[ky*7+5], k6 = kp[ky*7+6];
        ke[ky][0] = half2v{(_Float16)k0, (_Float16)k1};
        ke[ky][1] = half2v{(_Float16)k2, (_Float16)k3};
        ke[ky][2] = half2v{(_Float16)k4, (_Float16)k5};
        ke[ky][3] = half2v{(_Float16)k6, (_Float16)0.f};
        ko[ky][0] = half2v{(_Float16)0.f, (_Float16)k0};
        ko[ky][1] = half2v{(_Float16)k1, (_Float16)k2};
        ko[ky][2] = half2v{(_Float16)k3, (_Float16)k4};
        ko[ky][3] = half2v{(_Float16)k5, (_Float16)k6};
    }
    __syncthreads();

    const u16* plane = &tile[c * 898];
    for (int s2 = 0; s2 < 2; ++s2) {
        int seg = sh * 2 + s2;            // 0..3
        int o0 = seg * 14;                // output col base (even)
        float acc[14] = {0,0,0,0,0,0,0,0,0,0,0,0,0,0};
        #pragma unroll
        for (int ky = 0; ky < 7; ++ky) {
            const u16* rp = plane + (row + ky) * 64 + o0;
            half2v w2[10];
            #pragma unroll
            for (int t = 0; t < 10; ++t) w2[t] = *(const half2v*)(rp + t * 2);
            #pragma unroll
            for (int m = 0; m < 7; ++m) {
                float ae = acc[2*m], ao = acc[2*m+1];
                ae = __builtin_amdgcn_fdot2(w2[m],   ke[ky][0], ae, false);
                ae = __builtin_amdgcn_fdot2(w2[m+1], ke[ky][1], ae, false);
                ae = __builtin_amdgcn_fdot2(w2[m+2], ke[ky][2], ae, false);
                ae = __builtin_amdgcn_fdot2(w2[m+3], ke[ky][3], ae, false);
                ao = __builtin_amdgcn_fdot2(w2[m],   ko[ky][0], ao, false);
                ao = __builtin_amdgcn_fdot2(w2[m+1], ko[ky][1], ao, false);
                ao = __builtin_amdgcn_fdot2(w2[m+2], ko[ky][2], ao, false);
                ao = __builtin_amdgcn_fdot2(w2[m+3], ko[ky][3], ao, false);
                acc[2*m] = ae; acc[2*m+1] = ao;
            }
        }
        int h = rt * 8 + row;
        u16* op = dw + ((size_t)(n * 3136 + h * 56 + o0)) * 512 + cg * 16 + c;
        #pragma unroll
        for (int i = 0; i < 14; ++i)
            op[(size_t)i * 512] = f2h(acc[i]);
    }
}

extern "C" void kernel_launch(void* const* d_in, const int* in_sizes, int n_in,
                              void* d_out, int out_size, void* d_ws, size_t ws_size,
                              hipStream_t stream) {
    const float* x       = (const float*)d_in[0];
    // d_in[1] = k (=7), hardcoded
    const float* w_up    = (const float*)d_in[2];
    const float* b_up    = (const float*)d_in[3];
    const float* w_down  = (const float*)d_in[4];
    const float* b_down  = (const float*)d_in[5];
    const float* w_final = (const float*)d_in[6];
    const float* b_final = (const float*)d_in[7];

    char* ws = (char*)d_ws;
    u16*   xt     = (u16*)  (ws + 0);            // 102,760,448 B (x_t; later aliased as dw)
    u16*   up     = (u16*)  (ws + 102760448);    // 102,760,448 B
    float* pooled = (float*)(ws + 205520896);    // 3,211,264 B
    float* down   = (float*)(ws + 208732160);    // 3,211,264 B
    u16*   wub    = (u16*)  (ws + 211943424);    // 524,288 B
    u16*   wfb    = (u16*)  (ws + 212467712);    // 524,288 B
    u16*   dwb    = xt;                          // alias (x_t dead after up GEMM)

    cvtw_kernel<<<1024, 256, 0, stream>>>(w_up, w_final, wub, wfb);
    transpose_kernel<<<12544, 256, 0, stream>>>(x, xt);
    poolh_kernel<<<1568, 256, 0, stream>>>(xt, pooled);
    down_kernel<<<1024, 256, 0, stream>>>(pooled, w_down, b_down, down);
    gemm_kernel<0><<<3136, 256, 0, stream>>>(xt, wub, b_up, up);
    dw_kernel<<<7168, 256, 0, stream>>>(up, down, dwb);
    gemm_kernel<1><<<3136, 256, 0, stream>>>(wfb, dwb, b_final, d_out);
}

// Round 3
// 410.591 us; speedup vs baseline: 1.3101x; 1.1878x over previous
//
#include <hip/hip_runtime.h>
#include <hip/hip_bf16.h>

typedef unsigned short u16;
typedef _Float16 f16x8 __attribute__((ext_vector_type(8)));
typedef _Float16 f16x4 __attribute__((ext_vector_type(4)));
typedef _Float16 half2v __attribute__((ext_vector_type(2)));
typedef float f32x4 __attribute__((ext_vector_type(4)));
typedef unsigned short ushortx8 __attribute__((ext_vector_type(8)));
typedef unsigned short ushortx4 __attribute__((ext_vector_type(4)));

#define GPTR(p)  ((const __attribute__((address_space(1))) void*)(p))
#define LDSPTR(p) ((__attribute__((address_space(3))) void*)(p))

static __device__ __forceinline__ u16 f2h(float f) {
    _Float16 h = (_Float16)f;
    union { _Float16 h; u16 u; } v; v.h = h; return v.u;
}

// ---------------- weight convert: fp32 -> f16 ----------------
__global__ __launch_bounds__(256) void cvtw_kernel(
    const float* __restrict__ wu, const float* __restrict__ wf,
    u16* __restrict__ wub, u16* __restrict__ wfb) {
    int i = blockIdx.x * 256 + threadIdx.x;   // 262144 total
    wub[i] = f2h(wu[i]);
    wfb[i] = f2h(wf[i]);
}

// ---------------- transpose+convert: x[n][c][3136] fp32 -> x_t[n*3136+j][c] f16 ----------------
__global__ __launch_bounds__(256) void transpose_kernel(
    const float* __restrict__ x, u16* __restrict__ xt) {
    __shared__ float tile[64][65];
    int bid = blockIdx.x;
    int jt = bid % 49;
    int r = bid / 49;
    int ct = r & 7, n = r >> 3;
    const float* src = x + ((size_t)(n * 512 + ct * 64)) * 3136 + jt * 64;
    for (int e = threadIdx.x; e < 4096; e += 256) {
        int i = e >> 6, jj = e & 63;
        tile[i][jj] = src[(size_t)i * 3136 + jj];
    }
    __syncthreads();
    u16* dst = xt + ((size_t)(n * 3136 + jt * 64)) * 512 + ct * 64;
    for (int e = threadIdx.x; e < 2048; e += 256) {
        int jj = e >> 5, i2 = (e & 31) * 2;
        unsigned int val = (unsigned)f2h(tile[i2][jj]) | ((unsigned)f2h(tile[i2 + 1][jj]) << 16);
        *(unsigned int*)(dst + (size_t)jj * 512 + i2) = val;
    }
}

// ---------------- 8x8 avg pool from x_t f16: -> pooled[n][512][49] fp32 ----------------
__global__ __launch_bounds__(256) void poolh_kernel(
    const u16* __restrict__ xt, float* __restrict__ pooled) {
    int bid = blockIdx.x;                 // n(32) x py(7) x px(7)
    int n = bid / 49, cell = bid - n * 49;
    int py = cell / 7, px = cell - py * 7;
    int t = threadIdx.x;                  // channel pair 2t, 2t+1
    float s0 = 0.f, s1 = 0.f;
    for (int r = 0; r < 8; ++r) {
        int h = py * 8 + r;
        const u16* base = xt + ((size_t)(n * 3136 + h * 56 + px * 8)) * 512 + 2 * t;
        #pragma unroll
        for (int cc = 0; cc < 8; ++cc) {
            half2v v = *(const half2v*)(base + (size_t)cc * 512);
            s0 += (float)v[0]; s1 += (float)v[1];
        }
    }
    float* pp = pooled + (size_t)n * 512 * 49 + py * 7 + px;
    pp[(size_t)(2 * t) * 49]     = s0 * (1.f / 64.f);
    pp[(size_t)(2 * t + 1) * 49] = s1 * (1.f / 64.f);
}

// ---------------- down conv1x1: pooled[n][512][49] x w_down[512][512] -> down[n][512][49] fp32 ----------------
__global__ __launch_bounds__(256) void down_kernel(
    const float* __restrict__ pooled, const float* __restrict__ w_down,
    const float* __restrict__ b_down, float* __restrict__ down) {
    int bid = blockIdx.x;
    int n = bid >> 5, og = bid & 31;
    int wv = threadIdx.x >> 6, lane = threadIdx.x & 63;
    int o0 = og * 16 + wv * 4;
    const float* pp = pooled + (size_t)n * 512 * 49;
    const float* w0 = w_down + (size_t)o0 * 512;
    float a0 = 0, a1 = 0, a2 = 0, a3 = 0;
    int cell = lane < 49 ? lane : 48;
    #pragma unroll 4
    for (int c = 0; c < 512; ++c) {
        float p = pp[c * 49 + cell];
        a0 += p * w0[c];
        a1 += p * w0[512 + c];
        a2 += p * w0[1024 + c];
        a3 += p * w0[1536 + c];
    }
    if (lane < 49) {
        float* dd = down + ((size_t)n * 512 + o0) * 49 + lane;
        dd[0]   = a0 + b_down[o0];
        dd[49]  = a1 + b_down[o0 + 1];
        dd[98]  = a2 + b_down[o0 + 2];
        dd[147] = a3 + b_down[o0 + 3];
    }
}

// ---------------- GEMM (m97 structure, f16): C[m][n] = sum_k A[m][k] * Bt[n][k] ----------------
// EPI=0: up GEMM.  A=x_t [100352][512], Bt=w_up_f16 [512][512], bias by col,
//        output up_b BLOCKED: up_b[(J>>3)][512][J&7] f16
// EPI=1: final GEMM. A=w_final_f16 [512][512], Bt=dw [100352][512], bias by row, fp32 out NCHW
template <int EPI>
__global__ __launch_bounds__(256) void gemm_kernel(
    const u16* __restrict__ A, const u16* __restrict__ Bt,
    const float* __restrict__ bias, void* __restrict__ Cout) {
    constexpr int K = 512;
    __shared__ u16 As[128 * 32];
    __shared__ u16 Bs[128 * 32];
    int tid = threadIdx.x, wv = tid >> 6, lane = tid & 63;
    int bid = blockIdx.x;
    int tm, tn;
    // XCD-grouping swizzle: the 4 blocks sharing a 128-wide tile of the big
    // operand land on the same XCD (consecutive dispatch ids d, d+8, d+16, d+24).
    if (EPI == 0) { tm = (bid >> 5) * 8 + (bid & 7); tn = (bid >> 3) & 3; }
    else          { tn = (bid >> 5) * 8 + (bid & 7); tm = (bid >> 3) & 3; }
    size_t m0 = (size_t)tm * 128, n0 = (size_t)tn * 128;
    int lr = lane & 15, lk = (lane >> 4) * 8;
    int wr = wv >> 1, wc = wv & 1;

    int e0 = wv * 512 + lane * 8;
    int e1 = e0 + 2048;
    const u16* pa0 = A + (m0 + (size_t)(e0 >> 5)) * K + (e0 & 31);
    const u16* pa1 = A + (m0 + (size_t)(e1 >> 5)) * K + (e1 & 31);
    const u16* pb0 = Bt + (n0 + (size_t)(e0 >> 5)) * K + (e0 & 31);
    const u16* pb1 = Bt + (n0 + (size_t)(e1 >> 5)) * K + (e1 & 31);
    u16* sa0 = &As[wv * 512]; u16* sa1 = &As[wv * 512 + 2048];
    u16* sb0 = &Bs[wv * 512]; u16* sb1 = &Bs[wv * 512 + 2048];

    f32x4 acc[4][4] = {};

    for (int kt = 0; kt < K / 32; ++kt) {
        __builtin_amdgcn_global_load_lds(GPTR(pa0), LDSPTR(sa0), 16, 0, 0);
        __builtin_amdgcn_global_load_lds(GPTR(pa1), LDSPTR(sa1), 16, 0, 0);
        __builtin_amdgcn_global_load_lds(GPTR(pb0), LDSPTR(sb0), 16, 0, 0);
        __builtin_amdgcn_global_load_lds(GPTR(pb1), LDSPTR(sb1), 16, 0, 0);
        pa0 += 32; pa1 += 32; pb0 += 32; pb1 += 32;
        __syncthreads();
        f16x8 af[4], bfr[4];
        #pragma unroll
        for (int mi = 0; mi < 4; ++mi)
            af[mi] = *(const f16x8*)&As[(wr * 64 + mi * 16 + lr) * 32 + lk];
        #pragma unroll
        for (int ni = 0; ni < 4; ++ni)
            bfr[ni] = *(const f16x8*)&Bs[(wc * 64 + ni * 16 + lr) * 32 + lk];
        #pragma unroll
        for (int mi = 0; mi < 4; ++mi)
            #pragma unroll
            for (int ni = 0; ni < 4; ++ni)
                acc[mi][ni] = __builtin_amdgcn_mfma_f32_16x16x32_f16(af[mi], bfr[ni], acc[mi][ni], 0, 0, 0);
        __syncthreads();
    }

    if (EPI == 0) {
        u16* C = (u16*)Cout;   // blocked up_b
        #pragma unroll
        for (int ni = 0; ni < 4; ++ni) {
            size_t col = n0 + wc * 64 + ni * 16 + lr;          // channel
            float bv = bias[col];
            #pragma unroll
            for (int mi = 0; mi < 4; ++mi) {
                size_t rowb = m0 + wr * 64 + mi * 16 + (lane >> 4) * 4;   // J base (mult of 4)
                ushortx4 pack;
                #pragma unroll
                for (int r = 0; r < 4; ++r)
                    pack[r] = f2h(acc[mi][ni][r] + bv);
                *(ushortx4*)&C[(rowb >> 3) * 4096 + col * 8 + (rowb & 7)] = pack;
            }
        }
    } else {
        float* C = (float*)Cout;
        #pragma unroll
        for (int ni = 0; ni < 4; ++ni) {
            int col = (int)(n0 + wc * 64 + ni * 16 + lr);   // flat J
            int nimg = col / 3136;
            int jj = col - nimg * 3136;
            size_t obase = (size_t)nimg * 512 * 3136 + jj;
            #pragma unroll
            for (int mi = 0; mi < 4; ++mi) {
                int row = (int)(m0 + wr * 64 + mi * 16 + (lane >> 4) * 4);
                #pragma unroll
                for (int r = 0; r < 4; ++r)
                    C[obase + (size_t)(row + r) * 3136] = acc[mi][ni][r] + bias[row + r];
            }
        }
    }
}

// ---------------- dynamic depthwise 7x7 (f16, v_dot2_f32_f16, blocked input) ----------------
// up_b[(J>>3)][512][J&7] f16, down[n][512][49] fp32 -> dw[J][512] f16 (flat, for final GEMM)
// Block: 16 channels x 8 output rows x 56 cols. Grid: 32n x 7rt x 32cg = 7168.
// LDS planes [hh 14][c 16][72] f16; cols 0..55 data, 56..63 zeros (circular halo), 64..71 pad
// (72-stride -> 4-bank rotation per c -> ~2-way conflicts = free).
__global__ __launch_bounds__(256) void dw_kernel(
    const u16* __restrict__ upb, const float* __restrict__ down,
    u16* __restrict__ dw) {
    __shared__ u16 tile[14 * 16 * 72];        // 32256 B
    int bid = blockIdx.x;
    int n = bid / 224;                        // 7 * 32
    int rem = bid - n * 224;
    int rt = rem >> 5;                        // 0..6 (8 output rows each)
    int cg = rem & 31;                        // 16-ch group
    int tid = threadIdx.x;

    // zero the circular-halo columns 56..63 for all 224 (hh,c) rows
    if (tid < 224)
        *(ushortx8*)&tile[tid * 72 + 56] = (ushortx8)0;

    // stage 14 rows x 7 jb x 16 ch: one 16-B global read -> one ds_write_b128
    for (int e = tid; e < 1568; e += 256) {
        int c = e & 15;
        int p = e >> 4;                       // hh*7 + jb
        int hh = p / 7, jb = p - hh * 7;
        int h = rt * 8 + hh - 3;
        ushortx8 v = (ushortx8)0;
        if ((unsigned)h < 56u)
            v = *(const ushortx8*)(upb + ((size_t)(n * 392 + h * 7 + jb)) * 4096 + (cg * 16 + c) * 8);
        *(ushortx8*)&tile[(hh * 16 + c) * 72 + jb * 8] = v;
    }

    // kernel taps -> registers, two packings (even / odd output columns)
    int c = tid & 15, u = tid >> 4;
    int row = u >> 1, wh = u & 1, w0 = wh * 28;   // 28 output cols per thread
    const float* kp = down + ((size_t)n * 512 + cg * 16 + c) * 49;
    half2v kE[7][4], kO[7][4];
    #pragma unroll
    for (int ky = 0; ky < 7; ++ky) {
        float k0 = kp[ky*7+0], k1 = kp[ky*7+1], k2 = kp[ky*7+2], k3 = kp[ky*7+3];
        float k4 = kp[ky*7+4], k5 = kp[ky*7+5], k6 = kp[ky*7+6];
        kE[ky][0] = half2v{(_Float16)0.f, (_Float16)k0};
        kE[ky][1] = half2v{(_Float16)k1,  (_Float16)k2};
        kE[ky][2] = half2v{(_Float16)k3,  (_Float16)k4};
        kE[ky][3] = half2v{(_Float16)k5,  (_Float16)k6};
        kO[ky][0] = half2v{(_Float16)k0,  (_Float16)k1};
        kO[ky][1] = half2v{(_Float16)k2,  (_Float16)k3};
        kO[ky][2] = half2v{(_Float16)k4,  (_Float16)k5};
        kO[ky][3] = half2v{(_Float16)k6,  (_Float16)0.f};
    }
    __syncthreads();

    float acc[28];
    #pragma unroll
    for (int i = 0; i < 28; ++i) acc[i] = 0.f;

    #pragma unroll
    for (int ky = 0; ky < 7; ++ky) {
        const u16* rp = &tile[((row + ky) * 16 + c) * 72];
        // window pairs: global pair idx (w0/2 - 2 + t) for t=0..17, wrapped &31 (8-B aligned b64 loads)
        half2v w2[18];
        #pragma unroll
        for (int t = 0; t < 9; ++t) {
            int p0 = ((w0 >> 1) - 2 + 2 * t) & 31;
            f16x4 q = *(const f16x4*)(rp + p0 * 2);
            w2[2*t]   = half2v{q[0], q[1]};
            w2[2*t+1] = half2v{q[2], q[3]};
        }
        #pragma unroll
        for (int m = 0; m < 14; ++m) {
            float ae = acc[2*m], ao = acc[2*m+1];
            ae = __builtin_amdgcn_fdot2(w2[m],   kE[ky][0], ae, false);
            ae = __builtin_amdgcn_fdot2(w2[m+1], kE[ky][1], ae, false);
            ae = __builtin_amdgcn_fdot2(w2[m+2], kE[ky][2], ae, false);
            ae = __builtin_amdgcn_fdot2(w2[m+3], kE[ky][3], ae, false);
            ao = __builtin_amdgcn_fdot2(w2[m+1], kO[ky][0], ao, false);
            ao = __builtin_amdgcn_fdot2(w2[m+2], kO[ky][1], ao, false);
            ao = __builtin_amdgcn_fdot2(w2[m+3], kO[ky][2], ao, false);
            ao = __builtin_amdgcn_fdot2(w2[m+4], kO[ky][3], ao, false);
            acc[2*m] = ae; acc[2*m+1] = ao;
        }
    }

    int h = rt * 8 + row;
    u16* op = dw + ((size_t)(n * 3136 + h * 56 + w0)) * 512 + cg * 16 + c;
    #pragma unroll
    for (int i = 0; i < 28; ++i)
        op[(size_t)i * 512] = f2h(acc[i]);
}

extern "C" void kernel_launch(void* const* d_in, const int* in_sizes, int n_in,
                              void* d_out, int out_size, void* d_ws, size_t ws_size,
                              hipStream_t stream) {
    const float* x       = (const float*)d_in[0];
    // d_in[1] = k (=7), hardcoded
    const float* w_up    = (const float*)d_in[2];
    const float* b_up    = (const float*)d_in[3];
    const float* w_down  = (const float*)d_in[4];
    const float* b_down  = (const float*)d_in[5];
    const float* w_final = (const float*)d_in[6];
    const float* b_final = (const float*)d_in[7];

    char* ws = (char*)d_ws;
    u16*   xt     = (u16*)  (ws + 0);            // 102,760,448 B (x_t; later aliased as dw)
    u16*   upb    = (u16*)  (ws + 102760448);    // 102,760,448 B (blocked up)
    float* pooled = (float*)(ws + 205520896);    // 3,211,264 B
    float* down   = (float*)(ws + 208732160);    // 3,211,264 B
    u16*   wub    = (u16*)  (ws + 211943424);    // 524,288 B
    u16*   wfb    = (u16*)  (ws + 212467712);    // 524,288 B
    u16*   dwb    = xt;                          // alias (x_t dead after up GEMM)

    cvtw_kernel<<<1024, 256, 0, stream>>>(w_up, w_final, wub, wfb);
    transpose_kernel<<<12544, 256, 0, stream>>>(x, xt);
    poolh_kernel<<<1568, 256, 0, stream>>>(xt, pooled);
    down_kernel<<<1024, 256, 0, stream>>>(pooled, w_down, b_down, down);
    gemm_kernel<0><<<3136, 256, 0, stream>>>(xt, wub, b_up, upb);
    dw_kernel<<<7168, 256, 0, stream>>>(upb, down, dwb);
    gemm_kernel<1><<<3136, 256, 0, stream>>>(wfb, dwb, b_final, d_out);
}